// Round 1
// baseline (232.518 us; speedup 1.0000x reference)
//
#include <hip/hip_runtime.h>
#include <hip/hip_bf16.h>

#define NB 128
#define NQ 900
#define NT 256
#define NG 20
#define NR 15                 // pred rows per lane in match: 64*15 >= 900
#define FOCAL_BLOCKS 1800
#define MATCH_BLOCKS 128
#define TOTAL_BLOCKS (FOCAL_BLOCKS + MATCH_BLOCKS)
#define FWAVES (FOCAL_BLOCKS * 4)   // 7200 focal waves; x4 groups x4 rows = 115200 rows

// ws layout (floats): [0,7200) focal per-wave partials
//                     [7200,7328) bbox per-batch, [7328,7456) giou, [7456,7584) delta
#define WS_BB 7200
#define WS_GI 7328
#define WS_DL 7456

__device__ __forceinline__ float clamp01(float v) {
    return fminf(fmaxf(v, 0.0f), 1.0f);
}

// focal(x, target=0) WITHOUT the 0.75 alpha (folded into finalize).
__device__ __forceinline__ float focal_neg_term(float x) {
    float ax  = fabsf(x);
    float em  = __expf(-ax);
    float a1  = 1.0f + em;
    float ce  = fmaxf(x, 0.0f) + __logf(a1);
    float inv = __builtin_amdgcn_rcpf(a1);
    float p   = (x >= 0.0f) ? inv : em * inv;
    return ce * p * p;
}

// focal(x,1) - focal(x,0), full alpha factors included.
__device__ __forceinline__ float focal_delta_term(float x) {
    float ax     = fabsf(x);
    float em     = __expf(-ax);
    float a1     = 1.0f + em;
    float lg     = __logf(a1);
    float ce0    = fmaxf(x, 0.0f) + lg;
    float ce1    = ce0 - x;
    float inv    = __builtin_amdgcn_rcpf(a1);
    float em_inv = em * inv;
    float p      = (x >= 0.0f) ? inv : em_inv;   // sigmoid(x)
    float omp    = (x >= 0.0f) ? em_inv : inv;   // 1 - p
    return 0.25f * ce1 * omp * omp - 0.75f * ce0 * p * p;
}

// ---------------------------------------------------------------------------
// Fused kernel. Blocks [0,MATCH_BLOCKS): per-batch greedy match + bbox L1 +
// GIoU + span focal-correction. Box xyxy+area staged in LDS (18 KB) instead of
// 75 per-lane VGPRs so the WHOLE kernel fits <=64 VGPR -> 8 waves/EU.
// Blocks [MATCH_BLOCKS, TOTAL): focal(target=0) baseline over all logits,
// per-wave partial to ws. Memory-bound: needs full occupancy to hit HBM BW.
// __launch_bounds__(256, 8): 2nd arg = min waves per EU -> VGPR cap 64
// (occupancy halves crossing 64 VGPRs on gfx950).
// ---------------------------------------------------------------------------
__global__ __launch_bounds__(256, 8) void main_kernel(
    const float4* __restrict__ logits,      // [B*Q*T/4]
    const float4* __restrict__ pred_boxes,  // [B*Q] cxcywh
    const float4* __restrict__ tgt_boxes,   // [B*G] cxcywh
    const int2*   __restrict__ tokens,      // [B*G] (start, end)
    float*        __restrict__ ws)          // partials, see layout above
{
    // 18,080 B/block: 8 blocks/CU (144 KB <= 160 KB) == the 32-wave/CU cap.
    __shared__ float4 sxy[904];   // pred xyxy
    __shared__ float  sar[904];   // pred area

    if (blockIdx.x < MATCH_BLOCKS) {
        // ----------------- match path: one wave per batch -----------------
        const int b   = blockIdx.x;
        const int tid = threadIdx.x;

        // All 4 waves cooperatively stage pred boxes -> LDS (coalesced).
        for (int q = tid; q < 904; q += 256) {
            float4 xy; float a;
            if (q < NQ) {
                float4 pb = pred_boxes[b * NQ + q];
                xy.x = pb.x - 0.5f * pb.z;
                xy.y = pb.y - 0.5f * pb.w;
                xy.z = pb.x + 0.5f * pb.z;
                xy.w = pb.y + 0.5f * pb.w;
                a = (xy.z - xy.x) * (xy.w - xy.y);
            } else {
                xy = make_float4(2.0f, 2.0f, 2.0f, 2.0f);  // inert dummy row
                a  = 1.0f;                                  // avoids 0/0
            }
            sxy[q] = xy;
            sar[q] = a;
        }
        __syncthreads();
        if (tid >= 64) return;        // waves 1..3 done after staging
        const int lane = tid;

        // avail bit r <=> row q = lane + 64*r still unmatched (and q < 900).
        int avail = (lane < 4) ? 0x7fff : 0x3fff;   // r=14 valid only lane<4
        int my_q = 0;   // matched q for g == lane (lanes 0..19)

        for (int g = 0; g < NG; ++g) {
            float4 tb = tgt_boxes[b * NG + g];          // broadcast load (L1)
            float gx1 = tb.x - 0.5f * tb.z, gy1 = tb.y - 0.5f * tb.w;
            float gx2 = tb.x + 0.5f * tb.z, gy2 = tb.y + 0.5f * tb.w;
            float ga  = (gx2 - gx1) * (gy2 - gy1);
            float bv = -2.0f;
            int   bi = 0x7fffffff;
            #pragma unroll
            for (int r = 0; r < NR; ++r) {
                int q = lane + 64 * r;
                float4 p  = sxy[q];                     // ds_read_b128, conflict-free
                float  pa = sar[q];
                float ix1 = fmaxf(p.x, gx1), iy1 = fmaxf(p.y, gy1);
                float ix2 = fminf(p.z, gx2), iy2 = fminf(p.w, gy2);
                float iw = fmaxf(ix2 - ix1, 0.0f), ih = fmaxf(iy2 - iy1, 0.0f);
                float inter = iw * ih;
                float v = inter / (pa + ga - inter);    // exact div, matches ref
                bool ok = (avail >> r) & 1;
                v = ok ? v : -1.0f;                     // masked rows lose
                if (v > bv) { bv = v; bi = q; }         // strict >: first max per lane
            }
            #pragma unroll
            for (int off = 1; off < 64; off <<= 1) {
                float ov = __shfl_xor(bv, off);
                int   oi = __shfl_xor(bi, off);
                if (ov > bv || (ov == bv && oi < bi)) { bv = ov; bi = oi; }
            }
            if (lane == g) my_q = bi;
            if ((bi & 63) == lane) avail &= ~(1 << (bi >> 6));  // remove matched row
        }

        // Epilogue: bbox L1 + GIoU + span focal-correction for g = lane < 20.
        float lb = 0.0f, lgi = 0.0f, dl = 0.0f;
        if (lane < NG) {
            int g = lane, q = my_q;
            float4 pb = pred_boxes[b * NQ + q];
            float4 tb = tgt_boxes[b * NG + g];
            lb = fabsf(pb.x - tb.x) + fabsf(pb.y - tb.y) +
                 fabsf(pb.z - tb.z) + fabsf(pb.w - tb.w);

            float mx1 = pb.x - 0.5f * pb.z, my1 = pb.y - 0.5f * pb.w;
            float mx2 = pb.x + 0.5f * pb.z, my2 = pb.y + 0.5f * pb.w;
            mx2 = fmaxf(mx2, mx1 + 1e-6f);  my2 = fmaxf(my2, my1 + 1e-6f);
            mx1 = clamp01(mx1); my1 = clamp01(my1);
            mx2 = clamp01(mx2); my2 = clamp01(my2);

            float gx1 = tb.x - 0.5f * tb.z, gy1 = tb.y - 0.5f * tb.w;
            float gx2 = tb.x + 0.5f * tb.z, gy2 = tb.y + 0.5f * tb.w;
            gx2 = fmaxf(gx2, gx1 + 1e-6f);  gy2 = fmaxf(gy2, gy1 + 1e-6f);
            gx1 = clamp01(gx1); gy1 = clamp01(gy1);
            gx2 = clamp01(gx2); gy2 = clamp01(gy2);

            float a1 = (mx2 - mx1) * (my2 - my1);
            float a2 = (gx2 - gx1) * (gy2 - gy1);
            float ix1 = fmaxf(mx1, gx1), iy1 = fmaxf(my1, gy1);
            float ix2 = fminf(mx2, gx2), iy2 = fminf(my2, gy2);
            float iw = fmaxf(ix2 - ix1, 0.0f), ih = fmaxf(iy2 - iy1, 0.0f);
            float inter = iw * ih;
            float uni   = a1 + a2 - inter;
            float iou   = inter / uni;
            float cx1 = fminf(mx1, gx1), cy1 = fminf(my1, gy1);
            float cx2 = fmaxf(mx2, gx2), cy2 = fmaxf(my2, gy2);
            float ac  = fmaxf(cx2 - cx1, 0.0f) * fmaxf(cy2 - cy1, 0.0f);
            lgi = 1.0f - (iou - (ac - uni) / ac);

            // Span correction: sum focal(x,1)-focal(x,0) over the <=5 span tokens.
            int2 tk = tokens[b * NG + g];
            const float* rowp = (const float*)logits + (size_t)(b * NQ + q) * NT;
            for (int t = tk.x; t < tk.y; ++t) dl += focal_delta_term(rowp[t]);
        }
        #pragma unroll
        for (int off = 32; off > 0; off >>= 1) {
            lb  += __shfl_down(lb,  off);
            lgi += __shfl_down(lgi, off);
            dl  += __shfl_down(dl,  off);
        }
        if (lane == 0) {
            ws[WS_BB + b] = lb;
            ws[WS_GI + b] = lgi;
            ws[WS_DL + b] = dl;
        }
    } else {
        // ----------------- focal(target=0) baseline path -----------------
        const int lane = threadIdx.x & 63;
        const int gw   = ((blockIdx.x - MATCH_BLOCKS) * 256 + threadIdx.x) >> 6;

        float sum = 0.0f;
        #pragma unroll
        for (int i = 0; i < 4; ++i) {
            int row0 = (gw + i * FWAVES) * 4;
            float4 v0 = logits[(row0 + 0) * (NT / 4) + lane];
            float4 v1 = logits[(row0 + 1) * (NT / 4) + lane];
            float4 v2 = logits[(row0 + 2) * (NT / 4) + lane];
            float4 v3 = logits[(row0 + 3) * (NT / 4) + lane];
            sum += focal_neg_term(v0.x) + focal_neg_term(v0.y) +
                   focal_neg_term(v0.z) + focal_neg_term(v0.w);
            sum += focal_neg_term(v1.x) + focal_neg_term(v1.y) +
                   focal_neg_term(v1.z) + focal_neg_term(v1.w);
            sum += focal_neg_term(v2.x) + focal_neg_term(v2.y) +
                   focal_neg_term(v2.z) + focal_neg_term(v2.w);
            sum += focal_neg_term(v3.x) + focal_neg_term(v3.y) +
                   focal_neg_term(v3.z) + focal_neg_term(v3.w);
        }
        #pragma unroll
        for (int off = 32; off > 0; off >>= 1) sum += __shfl_down(sum, off);
        if (lane == 0) ws[gw] = sum;    // unconditional per-wave partial
    }
}

// ---------------------------------------------------------------------------
// Finalize: one block sums 7200 focal partials + 3x128 match partials,
// applies coefficients, writes the 4 outputs.
// ---------------------------------------------------------------------------
__global__ __launch_bounds__(256) void finalize_kernel(
    const float* __restrict__ ws, float* __restrict__ out)
{
    const int tid  = threadIdx.x;
    const int lane = tid & 63;
    const int wav  = tid >> 6;

    float s_neg = 0.0f;
    for (int i = tid; i < FWAVES; i += 256) s_neg += ws[i];
    float s_bb = 0.0f, s_gi = 0.0f, s_dl = 0.0f;
    if (tid < NB) {
        s_bb = ws[WS_BB + tid];
        s_gi = ws[WS_GI + tid];
        s_dl = ws[WS_DL + tid];
    }
    #pragma unroll
    for (int off = 32; off > 0; off >>= 1) {
        s_neg += __shfl_down(s_neg, off);
        s_bb  += __shfl_down(s_bb,  off);
        s_gi  += __shfl_down(s_gi,  off);
        s_dl  += __shfl_down(s_dl,  off);
    }
    __shared__ float red[4][4];
    if (lane == 0) {
        red[0][wav] = s_neg; red[1][wav] = s_bb;
        red[2][wav] = s_gi;  red[3][wav] = s_dl;
    }
    __syncthreads();
    if (tid == 0) {
        float neg = red[0][0] + red[0][1] + red[0][2] + red[0][3];
        float bb  = red[1][0] + red[1][1] + red[1][2] + red[1][3];
        float gi  = red[2][0] + red[2][1] + red[2][2] + red[2][3];
        float dlt = red[3][0] + red[3][1] + red[3][2] + red[3][3];
        const float num_boxes = (float)(NB * NG);          // 2560
        float lb = 5.0f * bb / num_boxes;
        float lg = 2.0f * gi / num_boxes;
        float cls_sum = 0.75f * neg + dlt;
        float lc = (cls_sum / (float)(NQ * NT)) / num_boxes;
        out[0] = lb;
        out[1] = lg;
        out[2] = lc;
        out[3] = lb + lg + lc;
    }
}

extern "C" void kernel_launch(void* const* d_in, const int* in_sizes, int n_in,
                              void* d_out, int out_size, void* d_ws, size_t ws_size,
                              hipStream_t stream) {
    const float4* pred_logits4 = (const float4*)d_in[0];  // (B,Q,T) f32
    const float4* pred_boxes4  = (const float4*)d_in[1];  // (B,Q,4) f32
    const float4* tgt_boxes4   = (const float4*)d_in[2];  // (B,G,4) f32
    const int2*   tokens2      = (const int2*)d_in[3];    // (B,G,2) i32

    float* ws = (float*)d_ws;   // 7584 floats, all slots written every call

    main_kernel<<<TOTAL_BLOCKS, 256, 0, stream>>>(pred_logits4, pred_boxes4,
                                                  tgt_boxes4, tokens2, ws);
    finalize_kernel<<<1, 256, 0, stream>>>(ws, (float*)d_out);
}

// Round 3
// 202.646 us; speedup vs baseline: 1.1474x; 1.1474x over previous
//
#include <hip/hip_runtime.h>
#include <hip/hip_bf16.h>

#define NB 128
#define NQ 900
#define NT 256
#define NG 20
#define NR 15                 // pred rows per lane in match: 64*15 >= 900
#define FOCAL_BLOCKS 1800
#define MATCH_BLOCKS 128
#define TOTAL_BLOCKS (FOCAL_BLOCKS + MATCH_BLOCKS)
#define FWAVES (FOCAL_BLOCKS * 4)   // 7200 focal waves; x4 groups x4 rows = 115200 rows

// ws layout (floats): [0,7200) focal per-wave partials
//                     [7200,7328) bbox per-batch, [7328,7456) giou, [7456,7584) delta
#define WS_BB 7200
#define WS_GI 7328
#define WS_DL 7456

__device__ __forceinline__ float clamp01(float v) {
    return fminf(fmaxf(v, 0.0f), 1.0f);
}

// focal(x, target=0) WITHOUT the 0.75 alpha (folded into finalize).
__device__ __forceinline__ float focal_neg_term(float x) {
    float ax  = fabsf(x);
    float em  = __expf(-ax);
    float a1  = 1.0f + em;
    float ce  = fmaxf(x, 0.0f) + __logf(a1);
    float inv = __builtin_amdgcn_rcpf(a1);
    float p   = (x >= 0.0f) ? inv : em * inv;
    return ce * p * p;
}

// focal(x,1) - focal(x,0), full alpha factors included.
__device__ __forceinline__ float focal_delta_term(float x) {
    float ax     = fabsf(x);
    float em     = __expf(-ax);
    float a1     = 1.0f + em;
    float lg     = __logf(a1);
    float ce0    = fmaxf(x, 0.0f) + lg;
    float ce1    = ce0 - x;
    float inv    = __builtin_amdgcn_rcpf(a1);
    float em_inv = em * inv;
    float p      = (x >= 0.0f) ? inv : em_inv;   // sigmoid(x)
    float omp    = (x >= 0.0f) ? em_inv : inv;   // 1 - p
    return 0.25f * ce1 * omp * omp - 0.75f * ce0 * p * p;
}

// ---------------------------------------------------------------------------
// Fused kernel, single register budget <=64 VGPR so ALL 1928 blocks are
// co-resident (8 blocks/CU with 18 KB LDS -> capacity 2048, single cohort).
// Round-1 lesson: forcing (256,8) with a 15-deep fully-unrolled match loop
// spilled the match branch to scratch (VGPR_Count=32, main=100us). Both
// branches are now written to FIT the budget:
//   - match r-loop: partial unroll 5 (~25 live regs, still hides ds_read)
//   - focal loop: explicit 2-stage pipeline, 8 float4 in flight (32 regs)
// ---------------------------------------------------------------------------
__global__ __launch_bounds__(256, 8) void main_kernel(
    const float4* __restrict__ logits,      // [B*Q*T/4]
    const float4* __restrict__ pred_boxes,  // [B*Q] cxcywh
    const float4* __restrict__ tgt_boxes,   // [B*G] cxcywh
    const int2*   __restrict__ tokens,      // [B*G] (start, end)
    float*        __restrict__ ws)          // partials, see layout above
{
    // 18,080 B/block: 8 blocks/CU (144 KB <= 160 KB) == the 32-wave/CU cap.
    __shared__ float4 sxy[904];   // pred xyxy
    __shared__ float  sar[904];   // pred area

    if (blockIdx.x < MATCH_BLOCKS) {
        // ----------------- match path: one wave per batch -----------------
        const int b   = blockIdx.x;
        const int tid = threadIdx.x;

        // All 4 waves cooperatively stage pred boxes -> LDS (coalesced).
        for (int q = tid; q < 904; q += 256) {
            float4 xy; float a;
            if (q < NQ) {
                float4 pb = pred_boxes[b * NQ + q];
                xy.x = pb.x - 0.5f * pb.z;
                xy.y = pb.y - 0.5f * pb.w;
                xy.z = pb.x + 0.5f * pb.z;
                xy.w = pb.y + 0.5f * pb.w;
                a = (xy.z - xy.x) * (xy.w - xy.y);
            } else {
                xy = make_float4(2.0f, 2.0f, 2.0f, 2.0f);  // inert dummy row
                a  = 1.0f;                                  // avoids 0/0
            }
            sxy[q] = xy;
            sar[q] = a;
        }
        __syncthreads();
        if (tid >= 64) return;        // waves 1..3 done after staging
        const int lane = tid;

        // avail bit r <=> row q = lane + 64*r still unmatched (and q < 900).
        int avail = (lane < 4) ? 0x7fff : 0x3fff;   // r=14 valid only lane<4
        int my_q = 0;   // matched q for g == lane (lanes 0..19)

        for (int g = 0; g < NG; ++g) {
            float4 tb = tgt_boxes[b * NG + g];          // broadcast load (L1)
            float gx1 = tb.x - 0.5f * tb.z, gy1 = tb.y - 0.5f * tb.w;
            float gx2 = tb.x + 0.5f * tb.z, gy2 = tb.y + 0.5f * tb.w;
            float ga  = (gx2 - gx1) * (gy2 - gy1);
            float bv = -2.0f;
            int   bi = 0x7fffffff;
            // Partial unroll: ~5 ds_read_b128 in flight is enough to cover
            // LDS latency without blowing the 64-VGPR budget (round-1 spill).
            #pragma unroll 5
            for (int r = 0; r < NR; ++r) {
                int q = lane + 64 * r;
                float4 p  = sxy[q];                     // ds_read_b128, conflict-free
                float  pa = sar[q];
                float ix1 = fmaxf(p.x, gx1), iy1 = fmaxf(p.y, gy1);
                float ix2 = fminf(p.z, gx2), iy2 = fminf(p.w, gy2);
                float iw = fmaxf(ix2 - ix1, 0.0f), ih = fmaxf(iy2 - iy1, 0.0f);
                float inter = iw * ih;
                float v = inter / (pa + ga - inter);    // exact div, matches ref
                bool ok = (avail >> r) & 1;
                v = ok ? v : -1.0f;                     // masked rows lose
                if (v > bv) { bv = v; bi = q; }         // strict >: first max per lane
            }
            #pragma unroll
            for (int off = 1; off < 64; off <<= 1) {
                float ov = __shfl_xor(bv, off);
                int   oi = __shfl_xor(bi, off);
                if (ov > bv || (ov == bv && oi < bi)) { bv = ov; bi = oi; }
            }
            if (lane == g) my_q = bi;
            if ((bi & 63) == lane) avail &= ~(1 << (bi >> 6));  // remove matched row
        }

        // Epilogue: bbox L1 + GIoU + span focal-correction for g = lane < 20.
        float lb = 0.0f, lgi = 0.0f, dl = 0.0f;
        if (lane < NG) {
            int g = lane, q = my_q;
            float4 pb = pred_boxes[b * NQ + q];
            float4 tb = tgt_boxes[b * NG + g];
            lb = fabsf(pb.x - tb.x) + fabsf(pb.y - tb.y) +
                 fabsf(pb.z - tb.z) + fabsf(pb.w - tb.w);

            float mx1 = pb.x - 0.5f * pb.z, my1 = pb.y - 0.5f * pb.w;
            float mx2 = pb.x + 0.5f * pb.z, my2 = pb.y + 0.5f * pb.w;
            mx2 = fmaxf(mx2, mx1 + 1e-6f);  my2 = fmaxf(my2, my1 + 1e-6f);
            mx1 = clamp01(mx1); my1 = clamp01(my1);
            mx2 = clamp01(mx2); my2 = clamp01(my2);

            float gx1 = tb.x - 0.5f * tb.z, gy1 = tb.y - 0.5f * tb.w;
            float gx2 = tb.x + 0.5f * tb.z, gy2 = tb.y + 0.5f * tb.w;
            gx2 = fmaxf(gx2, gx1 + 1e-6f);  gy2 = fmaxf(gy2, gy1 + 1e-6f);
            gx1 = clamp01(gx1); gy1 = clamp01(gy1);
            gx2 = clamp01(gx2); gy2 = clamp01(gy2);

            float a1 = (mx2 - mx1) * (my2 - my1);
            float a2 = (gx2 - gx1) * (gy2 - gy1);
            float ix1 = fmaxf(mx1, gx1), iy1 = fmaxf(my1, gy1);
            float ix2 = fminf(mx2, gx2), iy2 = fminf(my2, gy2);
            float iw = fmaxf(ix2 - ix1, 0.0f), ih = fmaxf(iy2 - iy1, 0.0f);
            float inter = iw * ih;
            float uni   = a1 + a2 - inter;
            float iou   = inter / uni;
            float cx1 = fminf(mx1, gx1), cy1 = fminf(my1, gy1);
            float cx2 = fmaxf(mx2, gx2), cy2 = fmaxf(my2, gy2);
            float ac  = fmaxf(cx2 - cx1, 0.0f) * fmaxf(cy2 - cy1, 0.0f);
            lgi = 1.0f - (iou - (ac - uni) / ac);

            // Span correction: sum focal(x,1)-focal(x,0) over the <=5 span tokens.
            int2 tk = tokens[b * NG + g];
            const float* rowp = (const float*)logits + (size_t)(b * NQ + q) * NT;
            for (int t = tk.x; t < tk.y; ++t) dl += focal_delta_term(rowp[t]);
        }
        #pragma unroll
        for (int off = 32; off > 0; off >>= 1) {
            lb  += __shfl_down(lb,  off);
            lgi += __shfl_down(lgi, off);
            dl  += __shfl_down(dl,  off);
        }
        if (lane == 0) {
            ws[WS_BB + b] = lb;
            ws[WS_GI + b] = lgi;
            ws[WS_DL + b] = dl;
        }
    } else {
        // ----------------- focal(target=0) baseline path -----------------
        // Explicit 2-stage software pipeline: 4 float4 current + 4 float4
        // prefetch = 8 independent loads in flight (32 VGPRs of data).
        // Summation order identical to baseline (bit-exact).
        const int lane = threadIdx.x & 63;
        const int gw   = ((blockIdx.x - MATCH_BLOCKS) * 256 + threadIdx.x) >> 6;
        const float4* __restrict__ base = logits + lane;   // lane column offset

        float sum = 0.0f;
        int row0 = gw * 4;                                  // group 0 rows
        float4 c0 = base[(size_t)(row0 + 0) * (NT / 4)];
        float4 c1 = base[(size_t)(row0 + 1) * (NT / 4)];
        float4 c2 = base[(size_t)(row0 + 2) * (NT / 4)];
        float4 c3 = base[(size_t)(row0 + 3) * (NT / 4)];
        #pragma unroll
        for (int i = 0; i < 4; ++i) {
            float4 n0, n1, n2, n3;
            if (i < 3) {
                int nr = (gw + (i + 1) * FWAVES) * 4;
                n0 = base[(size_t)(nr + 0) * (NT / 4)];
                n1 = base[(size_t)(nr + 1) * (NT / 4)];
                n2 = base[(size_t)(nr + 2) * (NT / 4)];
                n3 = base[(size_t)(nr + 3) * (NT / 4)];
            }
            sum += focal_neg_term(c0.x) + focal_neg_term(c0.y) +
                   focal_neg_term(c0.z) + focal_neg_term(c0.w);
            sum += focal_neg_term(c1.x) + focal_neg_term(c1.y) +
                   focal_neg_term(c1.z) + focal_neg_term(c1.w);
            sum += focal_neg_term(c2.x) + focal_neg_term(c2.y) +
                   focal_neg_term(c2.z) + focal_neg_term(c2.w);
            sum += focal_neg_term(c3.x) + focal_neg_term(c3.y) +
                   focal_neg_term(c3.z) + focal_neg_term(c3.w);
            if (i < 3) { c0 = n0; c1 = n1; c2 = n2; c3 = n3; }
        }
        #pragma unroll
        for (int off = 32; off > 0; off >>= 1) sum += __shfl_down(sum, off);
        if (lane == 0) ws[gw] = sum;    // unconditional per-wave partial
    }
}

// ---------------------------------------------------------------------------
// Finalize: one block sums 7200 focal partials + 3x128 match partials,
// applies coefficients, writes the 4 outputs.
// ---------------------------------------------------------------------------
__global__ __launch_bounds__(256) void finalize_kernel(
    const float* __restrict__ ws, float* __restrict__ out)
{
    const int tid  = threadIdx.x;
    const int lane = tid & 63;
    const int wav  = tid >> 6;

    float s_neg = 0.0f;
    for (int i = tid; i < FWAVES; i += 256) s_neg += ws[i];
    float s_bb = 0.0f, s_gi = 0.0f, s_dl = 0.0f;
    if (tid < NB) {
        s_bb = ws[WS_BB + tid];
        s_gi = ws[WS_GI + tid];
        s_dl = ws[WS_DL + tid];
    }
    #pragma unroll
    for (int off = 32; off > 0; off >>= 1) {
        s_neg += __shfl_down(s_neg, off);
        s_bb  += __shfl_down(s_bb,  off);
        s_gi  += __shfl_down(s_gi,  off);
        s_dl  += __shfl_down(s_dl,  off);
    }
    __shared__ float red[4][4];
    if (lane == 0) {
        red[0][wav] = s_neg; red[1][wav] = s_bb;
        red[2][wav] = s_gi;  red[3][wav] = s_dl;
    }
    __syncthreads();
    if (tid == 0) {
        float neg = red[0][0] + red[0][1] + red[0][2] + red[0][3];
        float bb  = red[1][0] + red[1][1] + red[1][2] + red[1][3];
        float gi  = red[2][0] + red[2][1] + red[2][2] + red[2][3];
        float dlt = red[3][0] + red[3][1] + red[3][2] + red[3][3];
        const float num_boxes = (float)(NB * NG);          // 2560
        float lb = 5.0f * bb / num_boxes;
        float lg = 2.0f * gi / num_boxes;
        float cls_sum = 0.75f * neg + dlt;
        float lc = (cls_sum / (float)(NQ * NT)) / num_boxes;
        out[0] = lb;
        out[1] = lg;
        out[2] = lc;
        out[3] = lb + lg + lc;
    }
}

extern "C" void kernel_launch(void* const* d_in, const int* in_sizes, int n_in,
                              void* d_out, int out_size, void* d_ws, size_t ws_size,
                              hipStream_t stream) {
    const float4* pred_logits4 = (const float4*)d_in[0];  // (B,Q,T) f32
    const float4* pred_boxes4  = (const float4*)d_in[1];  // (B,Q,4) f32
    const float4* tgt_boxes4   = (const float4*)d_in[2];  // (B,G,4) f32
    const int2*   tokens2      = (const int2*)d_in[3];    // (B,G,2) i32

    float* ws = (float*)d_ws;   // 7584 floats, all slots written every call

    main_kernel<<<TOTAL_BLOCKS, 256, 0, stream>>>(pred_logits4, pred_boxes4,
                                                  tgt_boxes4, tokens2, ws);
    finalize_kernel<<<1, 256, 0, stream>>>(ws, (float*)d_out);
}

// Round 4
// 187.332 us; speedup vs baseline: 1.2412x; 1.0817x over previous
//
#include <hip/hip_runtime.h>
#include <hip/hip_bf16.h>

#define NB 128
#define NQ 900
#define NT 256
#define NG 20
#define FOCAL_BLOCKS 1800
#define MATCH_BLOCKS 128
#define TOTAL_BLOCKS (FOCAL_BLOCKS + MATCH_BLOCKS)
#define FWAVES (FOCAL_BLOCKS * 4)   // 7200 focal waves; x4 groups x4 rows = 115200 rows

// ws layout (floats): [0,7200) focal per-wave partials
//                     [7200,7328) bbox per-batch, [7328,7456) giou, [7456,7584) delta
#define WS_BB 7200
#define WS_GI 7328
#define WS_DL 7456

__device__ __forceinline__ float clamp01(float v) {
    return fminf(fmaxf(v, 0.0f), 1.0f);
}

// focal(x, target=0) WITHOUT the 0.75 alpha (folded into finalize).
__device__ __forceinline__ float focal_neg_term(float x) {
    float ax  = fabsf(x);
    float em  = __expf(-ax);
    float a1  = 1.0f + em;
    float ce  = fmaxf(x, 0.0f) + __logf(a1);
    float inv = __builtin_amdgcn_rcpf(a1);
    float p   = (x >= 0.0f) ? inv : em * inv;
    return ce * p * p;
}

// focal(x,1) - focal(x,0), full alpha factors included.
__device__ __forceinline__ float focal_delta_term(float x) {
    float ax     = fabsf(x);
    float em     = __expf(-ax);
    float a1     = 1.0f + em;
    float lg     = __logf(a1);
    float ce0    = fmaxf(x, 0.0f) + lg;
    float ce1    = ce0 - x;
    float inv    = __builtin_amdgcn_rcpf(a1);
    float em_inv = em * inv;
    float p      = (x >= 0.0f) ? inv : em_inv;   // sigmoid(x)
    float omp    = (x >= 0.0f) ? em_inv : inv;   // 1 - p
    return 0.25f * ce1 * omp * omp - 0.75f * ce0 * p * p;
}

// ---------------------------------------------------------------------------
// Round-3 lesson: forcing __launch_bounds__(256,8) makes hipcc collapse to
// 28 VGPR, serializing BOTH branches; the serial 1-wave match path becomes a
// ~50us straggler tail (occupancy 33%, VALUBusy 29% = busy phase + idle tail).
// Fix: make match structurally register-light instead of capping registers.
//   - match: 4-wave cooperative. Thread t owns rows q = t + 256*r (r<4):
//     20 box regs/thread (vs 75), 4 register-resident IoUs per g-iter
//     (vs 15 LDS reads), tiny 32B LDS cross-wave argmax reduce.
//   - focal: explicit 2-stage pipeline, 8 float4 in flight, bit-exact order.
//   - NO min-waves clause: let the allocator breathe (~48-72 VGPR expected,
//     naturally 7-8 waves/EU with ~0 LDS).
// ---------------------------------------------------------------------------
__global__ __launch_bounds__(256) void main_kernel(
    const float4* __restrict__ logits,      // [B*Q*T/4]
    const float4* __restrict__ pred_boxes,  // [B*Q] cxcywh
    const float4* __restrict__ tgt_boxes,   // [B*G] cxcywh
    const int2*   __restrict__ tokens,      // [B*G] (start, end)
    float*        __restrict__ ws)          // partials, see layout above
{
    __shared__ float s_bv[4];   // per-wave best IoU
    __shared__ int   s_bi[4];   // per-wave best index

    if (blockIdx.x < MATCH_BLOCKS) {
        // ------------- match path: 4 waves cooperate on one batch ----------
        const int b    = blockIdx.x;
        const int tid  = threadIdx.x;
        const int lane = tid & 63;
        const int wav  = tid >> 6;

        // Thread t owns pred rows q = t + 256*r, r = 0..3 (1024 slots >= 900).
        float px1[4], py1[4], px2[4], py2[4], pa[4];
        #pragma unroll
        for (int r = 0; r < 4; ++r) {
            int q = tid + 256 * r;
            if (q < NQ) {
                float4 pb = pred_boxes[b * NQ + q];     // coalesced
                px1[r] = pb.x - 0.5f * pb.z; py1[r] = pb.y - 0.5f * pb.w;
                px2[r] = pb.x + 0.5f * pb.z; py2[r] = pb.y + 0.5f * pb.w;
                pa[r]  = (px2[r] - px1[r]) * (py2[r] - py1[r]);
            } else {
                px1[r] = 2.0f; py1[r] = 2.0f; px2[r] = 2.0f; py2[r] = 2.0f;
                pa[r]  = 1.0f;                          // inert, avoids 0/0
            }
        }
        // avail bit r <=> row q = tid + 256*r valid & unmatched.
        // q+768 < 900 iff tid < 132; q+512 always < 900.
        int avail = (tid < 132) ? 0xF : 0x7;
        int my_q  = 0;   // captured by thread g (g < 20 < 256)

        for (int g = 0; g < NG; ++g) {
            float4 tb = tgt_boxes[b * NG + g];          // broadcast load (L1)
            float gx1 = tb.x - 0.5f * tb.z, gy1 = tb.y - 0.5f * tb.w;
            float gx2 = tb.x + 0.5f * tb.z, gy2 = tb.y + 0.5f * tb.w;
            float ga  = (gx2 - gx1) * (gy2 - gy1);
            float bv = -2.0f;
            int   bi = 0x7fffffff;
            #pragma unroll
            for (int r = 0; r < 4; ++r) {
                float ix1 = fmaxf(px1[r], gx1), iy1 = fmaxf(py1[r], gy1);
                float ix2 = fminf(px2[r], gx2), iy2 = fminf(py2[r], gy2);
                float iw = fmaxf(ix2 - ix1, 0.0f), ih = fmaxf(iy2 - iy1, 0.0f);
                float inter = iw * ih;
                float v = inter / (pa[r] + ga - inter); // exact div, matches ref
                bool ok = (avail >> r) & 1;
                v = ok ? v : -1.0f;                     // masked rows lose
                int q = tid + 256 * r;
                if (v > bv) { bv = v; bi = q; }         // strict >: smallest q wins ties
            }
            // intra-wave argmax (value desc, index asc on ties)
            #pragma unroll
            for (int off = 1; off < 64; off <<= 1) {
                float ov = __shfl_xor(bv, off);
                int   oi = __shfl_xor(bi, off);
                if (ov > bv || (ov == bv && oi < bi)) { bv = ov; bi = oi; }
            }
            if (lane == 0) { s_bv[wav] = bv; s_bi[wav] = bi; }
            __syncthreads();
            // cross-wave argmax, computed redundantly by every thread
            float wbv = s_bv[0]; int wbi = s_bi[0];
            #pragma unroll
            for (int w = 1; w < 4; ++w) {
                float ov = s_bv[w]; int oi = s_bi[w];
                if (ov > wbv || (ov == wbv && oi < wbi)) { wbv = ov; wbi = oi; }
            }
            __syncthreads();   // all reads done before next iter's writes
            if (tid == g) my_q = wbi;
            if ((wbi & 255) == tid) avail &= ~(1 << (wbi >> 8));  // remove row
        }

        if (tid >= 64) return;   // epilogue + reduce on wave 0 only

        // Epilogue: bbox L1 + GIoU + span focal-correction for g = lane < 20.
        float lb = 0.0f, lgi = 0.0f, dl = 0.0f;
        if (lane < NG) {
            int g = lane, q = my_q;
            float4 pb = pred_boxes[b * NQ + q];
            float4 tb = tgt_boxes[b * NG + g];
            lb = fabsf(pb.x - tb.x) + fabsf(pb.y - tb.y) +
                 fabsf(pb.z - tb.z) + fabsf(pb.w - tb.w);

            float mx1 = pb.x - 0.5f * pb.z, my1 = pb.y - 0.5f * pb.w;
            float mx2 = pb.x + 0.5f * pb.z, my2 = pb.y + 0.5f * pb.w;
            mx2 = fmaxf(mx2, mx1 + 1e-6f);  my2 = fmaxf(my2, my1 + 1e-6f);
            mx1 = clamp01(mx1); my1 = clamp01(my1);
            mx2 = clamp01(mx2); my2 = clamp01(my2);

            float gx1 = tb.x - 0.5f * tb.z, gy1 = tb.y - 0.5f * tb.w;
            float gx2 = tb.x + 0.5f * tb.z, gy2 = tb.y + 0.5f * tb.w;
            gx2 = fmaxf(gx2, gx1 + 1e-6f);  gy2 = fmaxf(gy2, gy1 + 1e-6f);
            gx1 = clamp01(gx1); gy1 = clamp01(gy1);
            gx2 = clamp01(gx2); gy2 = clamp01(gy2);

            float a1 = (mx2 - mx1) * (my2 - my1);
            float a2 = (gx2 - gx1) * (gy2 - gy1);
            float ix1 = fmaxf(mx1, gx1), iy1 = fmaxf(my1, gy1);
            float ix2 = fminf(mx2, gx2), iy2 = fminf(my2, gy2);
            float iw = fmaxf(ix2 - ix1, 0.0f), ih = fmaxf(iy2 - iy1, 0.0f);
            float inter = iw * ih;
            float uni   = a1 + a2 - inter;
            float iou   = inter / uni;
            float cx1 = fminf(mx1, gx1), cy1 = fminf(my1, gy1);
            float cx2 = fmaxf(mx2, gx2), cy2 = fmaxf(my2, gy2);
            float ac  = fmaxf(cx2 - cx1, 0.0f) * fmaxf(cy2 - cy1, 0.0f);
            lgi = 1.0f - (iou - (ac - uni) / ac);

            // Span correction: sum focal(x,1)-focal(x,0) over the <=5 span tokens.
            int2 tk = tokens[b * NG + g];
            const float* rowp = (const float*)logits + (size_t)(b * NQ + q) * NT;
            for (int t = tk.x; t < tk.y; ++t) dl += focal_delta_term(rowp[t]);
        }
        #pragma unroll
        for (int off = 32; off > 0; off >>= 1) {
            lb  += __shfl_down(lb,  off);
            lgi += __shfl_down(lgi, off);
            dl  += __shfl_down(dl,  off);
        }
        if (lane == 0) {
            ws[WS_BB + b] = lb;
            ws[WS_GI + b] = lgi;
            ws[WS_DL + b] = dl;
        }
    } else {
        // ----------------- focal(target=0) baseline path -----------------
        // Explicit 2-stage software pipeline: 4 float4 current + 4 float4
        // prefetch = 8 independent loads in flight (32 VGPRs of data).
        // Summation order identical to baseline (bit-exact).
        const int lane = threadIdx.x & 63;
        const int gw   = ((blockIdx.x - MATCH_BLOCKS) * 256 + threadIdx.x) >> 6;
        const float4* __restrict__ base = logits + lane;   // lane column offset

        float sum = 0.0f;
        int row0 = gw * 4;                                  // group 0 rows
        float4 c0 = base[(size_t)(row0 + 0) * (NT / 4)];
        float4 c1 = base[(size_t)(row0 + 1) * (NT / 4)];
        float4 c2 = base[(size_t)(row0 + 2) * (NT / 4)];
        float4 c3 = base[(size_t)(row0 + 3) * (NT / 4)];
        #pragma unroll
        for (int i = 0; i < 4; ++i) {
            float4 n0, n1, n2, n3;
            if (i < 3) {
                int nr = (gw + (i + 1) * FWAVES) * 4;
                n0 = base[(size_t)(nr + 0) * (NT / 4)];
                n1 = base[(size_t)(nr + 1) * (NT / 4)];
                n2 = base[(size_t)(nr + 2) * (NT / 4)];
                n3 = base[(size_t)(nr + 3) * (NT / 4)];
            }
            sum += focal_neg_term(c0.x) + focal_neg_term(c0.y) +
                   focal_neg_term(c0.z) + focal_neg_term(c0.w);
            sum += focal_neg_term(c1.x) + focal_neg_term(c1.y) +
                   focal_neg_term(c1.z) + focal_neg_term(c1.w);
            sum += focal_neg_term(c2.x) + focal_neg_term(c2.y) +
                   focal_neg_term(c2.z) + focal_neg_term(c2.w);
            sum += focal_neg_term(c3.x) + focal_neg_term(c3.y) +
                   focal_neg_term(c3.z) + focal_neg_term(c3.w);
            if (i < 3) { c0 = n0; c1 = n1; c2 = n2; c3 = n3; }
        }
        #pragma unroll
        for (int off = 32; off > 0; off >>= 1) sum += __shfl_down(sum, off);
        if (lane == 0) ws[gw] = sum;    // unconditional per-wave partial
    }
}

// ---------------------------------------------------------------------------
// Finalize: one block sums 7200 focal partials + 3x128 match partials,
// applies coefficients, writes the 4 outputs.
// ---------------------------------------------------------------------------
__global__ __launch_bounds__(256) void finalize_kernel(
    const float* __restrict__ ws, float* __restrict__ out)
{
    const int tid  = threadIdx.x;
    const int lane = tid & 63;
    const int wav  = tid >> 6;

    float s_neg = 0.0f;
    for (int i = tid; i < FWAVES; i += 256) s_neg += ws[i];
    float s_bb = 0.0f, s_gi = 0.0f, s_dl = 0.0f;
    if (tid < NB) {
        s_bb = ws[WS_BB + tid];
        s_gi = ws[WS_GI + tid];
        s_dl = ws[WS_DL + tid];
    }
    #pragma unroll
    for (int off = 32; off > 0; off >>= 1) {
        s_neg += __shfl_down(s_neg, off);
        s_bb  += __shfl_down(s_bb,  off);
        s_gi  += __shfl_down(s_gi,  off);
        s_dl  += __shfl_down(s_dl,  off);
    }
    __shared__ float red[4][4];
    if (lane == 0) {
        red[0][wav] = s_neg; red[1][wav] = s_bb;
        red[2][wav] = s_gi;  red[3][wav] = s_dl;
    }
    __syncthreads();
    if (tid == 0) {
        float neg = red[0][0] + red[0][1] + red[0][2] + red[0][3];
        float bb  = red[1][0] + red[1][1] + red[1][2] + red[1][3];
        float gi  = red[2][0] + red[2][1] + red[2][2] + red[2][3];
        float dlt = red[3][0] + red[3][1] + red[3][2] + red[3][3];
        const float num_boxes = (float)(NB * NG);          // 2560
        float lb = 5.0f * bb / num_boxes;
        float lg = 2.0f * gi / num_boxes;
        float cls_sum = 0.75f * neg + dlt;
        float lc = (cls_sum / (float)(NQ * NT)) / num_boxes;
        out[0] = lb;
        out[1] = lg;
        out[2] = lc;
        out[3] = lb + lg + lc;
    }
}

extern "C" void kernel_launch(void* const* d_in, const int* in_sizes, int n_in,
                              void* d_out, int out_size, void* d_ws, size_t ws_size,
                              hipStream_t stream) {
    const float4* pred_logits4 = (const float4*)d_in[0];  // (B,Q,T) f32
    const float4* pred_boxes4  = (const float4*)d_in[1];  // (B,Q,4) f32
    const float4* tgt_boxes4   = (const float4*)d_in[2];  // (B,G,4) f32
    const int2*   tokens2      = (const int2*)d_in[3];    // (B,G,2) i32

    float* ws = (float*)d_ws;   // 7584 floats, all slots written every call

    main_kernel<<<TOTAL_BLOCKS, 256, 0, stream>>>(pred_logits4, pred_boxes4,
                                                  tgt_boxes4, tokens2, ws);
    finalize_kernel<<<1, 256, 0, stream>>>(ws, (float*)d_out);
}

// Round 5
// 184.967 us; speedup vs baseline: 1.2571x; 1.0128x over previous
//
#include <hip/hip_runtime.h>
#include <hip/hip_bf16.h>

#define NB 128
#define NQ 900
#define NT 256
#define NG 20
#define FOCAL_BLOCKS 1800
#define MATCH_BLOCKS 128
#define TOTAL_BLOCKS (FOCAL_BLOCKS + MATCH_BLOCKS)
#define FWAVES (FOCAL_BLOCKS * 4)   // 7200 focal waves; x4 groups x4 rows = 115200 rows

// ws layout (floats): [0,7200) focal per-wave partials
//                     [7200,7328) bbox per-batch, [7328,7456) giou, [7456,7584) delta
#define WS_BB 7200
#define WS_GI 7328
#define WS_DL 7456

__device__ __forceinline__ float clamp01(float v) {
    return fminf(fmaxf(v, 0.0f), 1.0f);
}

// focal(x, target=0) WITHOUT the 0.75 alpha (folded into finalize).
__device__ __forceinline__ float focal_neg_term(float x) {
    float ax  = fabsf(x);
    float em  = __expf(-ax);
    float a1  = 1.0f + em;
    float ce  = fmaxf(x, 0.0f) + __logf(a1);
    float inv = __builtin_amdgcn_rcpf(a1);
    float p   = (x >= 0.0f) ? inv : em * inv;
    return ce * p * p;
}

// focal(x,1) - focal(x,0), full alpha factors included.
__device__ __forceinline__ float focal_delta_term(float x) {
    float ax     = fabsf(x);
    float em     = __expf(-ax);
    float a1     = 1.0f + em;
    float lg     = __logf(a1);
    float ce0    = fmaxf(x, 0.0f) + lg;
    float ce1    = ce0 - x;
    float inv    = __builtin_amdgcn_rcpf(a1);
    float em_inv = em * inv;
    float p      = (x >= 0.0f) ? inv : em_inv;   // sigmoid(x)
    float omp    = (x >= 0.0f) ? em_inv : inv;   // 1 - p
    return 0.25f * ce1 * omp * omp - 0.75f * ce0 * p * p;
}

// ---------------------------------------------------------------------------
// Session synthesis (R0-R4):
//  - No cap + any match  -> VGPR 65-128 -> 4 blocks/CU -> focal runs in TWO
//    cohorts (~2x20us). R0/R4 totals identical at 187us: main ~40us.
//  - (256,8) + serial/pipelined code -> collapse to 28-32 VGPR, spills,
//    straggler match (R1: 100us, R3: 76us).
//  - THIS version: (256,8) + branches that FIT a collapsed budget:
//      match: 4-wave cooperative, 4 boxes/thread (~20 data regs, 4-deep
//             independent IoUs, immune to the cap; proven in R4)
//      focal: simple R0-style loop (4x4 float4 groups, ~26 live regs;
//             BW-bound at ANY occupancy >= 2 loads in flight, so even a
//             28-VGPR collapse keeps it at the HBM ceiling)
//    => all 1928 blocks co-resident (8 blocks/CU, LDS 32B), single cohort.
// ---------------------------------------------------------------------------
__global__ __launch_bounds__(256, 8) void main_kernel(
    const float4* __restrict__ logits,      // [B*Q*T/4]
    const float4* __restrict__ pred_boxes,  // [B*Q] cxcywh
    const float4* __restrict__ tgt_boxes,   // [B*G] cxcywh
    const int2*   __restrict__ tokens,      // [B*G] (start, end)
    float*        __restrict__ ws)          // partials, see layout above
{
    __shared__ float s_bv[4];   // per-wave best IoU
    __shared__ int   s_bi[4];   // per-wave best index

    if (blockIdx.x < MATCH_BLOCKS) {
        // ------------- match path: 4 waves cooperate on one batch ----------
        const int b    = blockIdx.x;
        const int tid  = threadIdx.x;
        const int lane = tid & 63;
        const int wav  = tid >> 6;

        // Thread t owns pred rows q = t + 256*r, r = 0..3 (1024 slots >= 900).
        float px1[4], py1[4], px2[4], py2[4], pa[4];
        #pragma unroll
        for (int r = 0; r < 4; ++r) {
            int q = tid + 256 * r;
            if (q < NQ) {
                float4 pb = pred_boxes[b * NQ + q];     // coalesced
                px1[r] = pb.x - 0.5f * pb.z; py1[r] = pb.y - 0.5f * pb.w;
                px2[r] = pb.x + 0.5f * pb.z; py2[r] = pb.y + 0.5f * pb.w;
                pa[r]  = (px2[r] - px1[r]) * (py2[r] - py1[r]);
            } else {
                px1[r] = 2.0f; py1[r] = 2.0f; px2[r] = 2.0f; py2[r] = 2.0f;
                pa[r]  = 1.0f;                          // inert, avoids 0/0
            }
        }
        // avail bit r <=> row q = tid + 256*r valid & unmatched.
        // q+768 < 900 iff tid < 132; q+512 always < 900.
        int avail = (tid < 132) ? 0xF : 0x7;
        int my_q  = 0;   // captured by thread g (g < 20 < 256)

        for (int g = 0; g < NG; ++g) {
            float4 tb = tgt_boxes[b * NG + g];          // broadcast load (L1)
            float gx1 = tb.x - 0.5f * tb.z, gy1 = tb.y - 0.5f * tb.w;
            float gx2 = tb.x + 0.5f * tb.z, gy2 = tb.y + 0.5f * tb.w;
            float ga  = (gx2 - gx1) * (gy2 - gy1);
            float bv = -2.0f;
            int   bi = 0x7fffffff;
            #pragma unroll
            for (int r = 0; r < 4; ++r) {
                float ix1 = fmaxf(px1[r], gx1), iy1 = fmaxf(py1[r], gy1);
                float ix2 = fminf(px2[r], gx2), iy2 = fminf(py2[r], gy2);
                float iw = fmaxf(ix2 - ix1, 0.0f), ih = fmaxf(iy2 - iy1, 0.0f);
                float inter = iw * ih;
                float v = inter / (pa[r] + ga - inter); // exact div, matches ref
                bool ok = (avail >> r) & 1;
                v = ok ? v : -1.0f;                     // masked rows lose
                int q = tid + 256 * r;
                if (v > bv) { bv = v; bi = q; }         // strict >: smallest q wins ties
            }
            // intra-wave argmax (value desc, index asc on ties)
            #pragma unroll
            for (int off = 1; off < 64; off <<= 1) {
                float ov = __shfl_xor(bv, off);
                int   oi = __shfl_xor(bi, off);
                if (ov > bv || (ov == bv && oi < bi)) { bv = ov; bi = oi; }
            }
            if (lane == 0) { s_bv[wav] = bv; s_bi[wav] = bi; }
            __syncthreads();
            // cross-wave argmax, computed redundantly by every thread
            float wbv = s_bv[0]; int wbi = s_bi[0];
            #pragma unroll
            for (int w = 1; w < 4; ++w) {
                float ov = s_bv[w]; int oi = s_bi[w];
                if (ov > wbv || (ov == wbv && oi < wbi)) { wbv = ov; wbi = oi; }
            }
            __syncthreads();   // all reads done before next iter's writes
            if (tid == g) my_q = wbi;
            if ((wbi & 255) == tid) avail &= ~(1 << (wbi >> 8));  // remove row
        }

        if (tid >= 64) return;   // epilogue + reduce on wave 0 only

        // Epilogue: bbox L1 + GIoU + span focal-correction for g = lane < 20.
        float lb = 0.0f, lgi = 0.0f, dl = 0.0f;
        if (lane < NG) {
            int g = lane, q = my_q;
            float4 pb = pred_boxes[b * NQ + q];
            float4 tb = tgt_boxes[b * NG + g];
            lb = fabsf(pb.x - tb.x) + fabsf(pb.y - tb.y) +
                 fabsf(pb.z - tb.z) + fabsf(pb.w - tb.w);

            float mx1 = pb.x - 0.5f * pb.z, my1 = pb.y - 0.5f * pb.w;
            float mx2 = pb.x + 0.5f * pb.z, my2 = pb.y + 0.5f * pb.w;
            mx2 = fmaxf(mx2, mx1 + 1e-6f);  my2 = fmaxf(my2, my1 + 1e-6f);
            mx1 = clamp01(mx1); my1 = clamp01(my1);
            mx2 = clamp01(mx2); my2 = clamp01(my2);

            float gx1 = tb.x - 0.5f * tb.z, gy1 = tb.y - 0.5f * tb.w;
            float gx2 = tb.x + 0.5f * tb.z, gy2 = tb.y + 0.5f * tb.w;
            gx2 = fmaxf(gx2, gx1 + 1e-6f);  gy2 = fmaxf(gy2, gy1 + 1e-6f);
            gx1 = clamp01(gx1); gy1 = clamp01(gy1);
            gx2 = clamp01(gx2); gy2 = clamp01(gy2);

            float a1 = (mx2 - mx1) * (my2 - my1);
            float a2 = (gx2 - gx1) * (gy2 - gy1);
            float ix1 = fmaxf(mx1, gx1), iy1 = fmaxf(my1, gy1);
            float ix2 = fminf(mx2, gx2), iy2 = fminf(my2, gy2);
            float iw = fmaxf(ix2 - ix1, 0.0f), ih = fmaxf(iy2 - iy1, 0.0f);
            float inter = iw * ih;
            float uni   = a1 + a2 - inter;
            float iou   = inter / uni;
            float cx1 = fminf(mx1, gx1), cy1 = fminf(my1, gy1);
            float cx2 = fmaxf(mx2, gx2), cy2 = fmaxf(my2, gy2);
            float ac  = fmaxf(cx2 - cx1, 0.0f) * fmaxf(cy2 - cy1, 0.0f);
            lgi = 1.0f - (iou - (ac - uni) / ac);

            // Span correction: sum focal(x,1)-focal(x,0) over the <=5 span tokens.
            int2 tk = tokens[b * NG + g];
            const float* rowp = (const float*)logits + (size_t)(b * NQ + q) * NT;
            for (int t = tk.x; t < tk.y; ++t) dl += focal_delta_term(rowp[t]);
        }
        #pragma unroll
        for (int off = 32; off > 0; off >>= 1) {
            lb  += __shfl_down(lb,  off);
            lgi += __shfl_down(lgi, off);
            dl  += __shfl_down(dl,  off);
        }
        if (lane == 0) {
            ws[WS_BB + b] = lb;
            ws[WS_GI + b] = lgi;
            ws[WS_DL + b] = dl;
        }
    } else {
        // ----------------- focal(target=0) baseline path -----------------
        // Simple 4-group loop (R0 style): 4 float4 loads issued per group,
        // ~26 live VGPRs -- fits even a compiler-collapsed budget. BW-bound
        // at full occupancy (8 blocks/CU). Summation order bit-exact.
        const int lane = threadIdx.x & 63;
        const int gw   = ((blockIdx.x - MATCH_BLOCKS) * 256 + threadIdx.x) >> 6;

        float sum = 0.0f;
        #pragma unroll
        for (int i = 0; i < 4; ++i) {
            int row0 = (gw + i * FWAVES) * 4;
            float4 v0 = logits[(size_t)(row0 + 0) * (NT / 4) + lane];
            float4 v1 = logits[(size_t)(row0 + 1) * (NT / 4) + lane];
            float4 v2 = logits[(size_t)(row0 + 2) * (NT / 4) + lane];
            float4 v3 = logits[(size_t)(row0 + 3) * (NT / 4) + lane];
            sum += focal_neg_term(v0.x) + focal_neg_term(v0.y) +
                   focal_neg_term(v0.z) + focal_neg_term(v0.w);
            sum += focal_neg_term(v1.x) + focal_neg_term(v1.y) +
                   focal_neg_term(v1.z) + focal_neg_term(v1.w);
            sum += focal_neg_term(v2.x) + focal_neg_term(v2.y) +
                   focal_neg_term(v2.z) + focal_neg_term(v2.w);
            sum += focal_neg_term(v3.x) + focal_neg_term(v3.y) +
                   focal_neg_term(v3.z) + focal_neg_term(v3.w);
        }
        #pragma unroll
        for (int off = 32; off > 0; off >>= 1) sum += __shfl_down(sum, off);
        if (lane == 0) ws[gw] = sum;    // unconditional per-wave partial
    }
}

// ---------------------------------------------------------------------------
// Finalize: one block sums 7200 focal partials + 3x128 match partials,
// applies coefficients, writes the 4 outputs.
// ---------------------------------------------------------------------------
__global__ __launch_bounds__(256) void finalize_kernel(
    const float* __restrict__ ws, float* __restrict__ out)
{
    const int tid  = threadIdx.x;
    const int lane = tid & 63;
    const int wav  = tid >> 6;

    float s_neg = 0.0f;
    for (int i = tid; i < FWAVES; i += 256) s_neg += ws[i];
    float s_bb = 0.0f, s_gi = 0.0f, s_dl = 0.0f;
    if (tid < NB) {
        s_bb = ws[WS_BB + tid];
        s_gi = ws[WS_GI + tid];
        s_dl = ws[WS_DL + tid];
    }
    #pragma unroll
    for (int off = 32; off > 0; off >>= 1) {
        s_neg += __shfl_down(s_neg, off);
        s_bb  += __shfl_down(s_bb,  off);
        s_gi  += __shfl_down(s_gi,  off);
        s_dl  += __shfl_down(s_dl,  off);
    }
    __shared__ float red[4][4];
    if (lane == 0) {
        red[0][wav] = s_neg; red[1][wav] = s_bb;
        red[2][wav] = s_gi;  red[3][wav] = s_dl;
    }
    __syncthreads();
    if (tid == 0) {
        float neg = red[0][0] + red[0][1] + red[0][2] + red[0][3];
        float bb  = red[1][0] + red[1][1] + red[1][2] + red[1][3];
        float gi  = red[2][0] + red[2][1] + red[2][2] + red[2][3];
        float dlt = red[3][0] + red[3][1] + red[3][2] + red[3][3];
        const float num_boxes = (float)(NB * NG);          // 2560
        float lb = 5.0f * bb / num_boxes;
        float lg = 2.0f * gi / num_boxes;
        float cls_sum = 0.75f * neg + dlt;
        float lc = (cls_sum / (float)(NQ * NT)) / num_boxes;
        out[0] = lb;
        out[1] = lg;
        out[2] = lc;
        out[3] = lb + lg + lc;
    }
}

extern "C" void kernel_launch(void* const* d_in, const int* in_sizes, int n_in,
                              void* d_out, int out_size, void* d_ws, size_t ws_size,
                              hipStream_t stream) {
    const float4* pred_logits4 = (const float4*)d_in[0];  // (B,Q,T) f32
    const float4* pred_boxes4  = (const float4*)d_in[1];  // (B,Q,4) f32
    const float4* tgt_boxes4   = (const float4*)d_in[2];  // (B,G,4) f32
    const int2*   tokens2      = (const int2*)d_in[3];    // (B,G,2) i32

    float* ws = (float*)d_ws;   // 7584 floats, all slots written every call

    main_kernel<<<TOTAL_BLOCKS, 256, 0, stream>>>(pred_logits4, pred_boxes4,
                                                  tgt_boxes4, tokens2, ws);
    finalize_kernel<<<1, 256, 0, stream>>>(ws, (float*)d_out);
}